// Round 1
// baseline (176.423 us; speedup 1.0000x reference)
//
#include <hip/hip_runtime.h>
#include <cstddef>

#define N_ 16
#define L_ 512
#define D_ 256
#define M_ 3584
#define K_ 3
#define LN_EPS 1e-5f

// ---------------------------------------------------------------- cumsum ----
// one block per n, 512 threads, inclusive scan of target -> ends
__global__ void cumsum_kernel(const int* __restrict__ target, int* __restrict__ ends) {
    __shared__ int s[L_];
    int n = blockIdx.x, t = threadIdx.x;
    s[t] = target[n * L_ + t];
    __syncthreads();
    for (int off = 1; off < L_; off <<= 1) {
        int v = (t >= off) ? s[t - off] : 0;
        __syncthreads();
        s[t] += v;
        __syncthreads();
    }
    ends[n * L_ + t] = s[t];
}

// ---------------------------------------------------------------- conv ------
// y[n,l,co] = sum_{k,ci} x[n, l+k-1, ci] * W[k,ci,co] + bias[co]; relu.
// Block: 256 threads = 4 waves. Tile: 64 l (lane = l) x 32 co.
// Wave w handles co_base = blockIdx.y*32 + w*8, uniform -> scalar weight loads.
// x staged in LDS in 2 ci-chunks of 128; row stride 132 floats:
//   132*4 = 528 B, 528 % 16 == 0 (b128-aligned); 132/4 = 33 === 1 (mod 8)
//   -> consecutive lanes hit consecutive 16B superbanks (conflict-free).
#define TL 64
#define CCH 128
#define XROW (CCH + 4)
#define CO_SPLIT 8

__global__ __launch_bounds__(256)
void conv_relu_kernel(const float* __restrict__ in, const float* __restrict__ W,
                      const float* __restrict__ bias, float* __restrict__ out) {
    __shared__ float xs[(TL + 2) * XROW];
    const int l0 = blockIdx.x * TL;
    const int co0 = blockIdx.y * (D_ / CO_SPLIT);   // 32-wide co block
    const int n = blockIdx.z;
    const int tid = threadIdx.x;
    const int lane = tid & 63;
    const int wv = tid >> 6;
    const int co_base = __builtin_amdgcn_readfirstlane(co0 + wv * 8);

    float acc[8];
#pragma unroll
    for (int j = 0; j < 8; ++j) acc[j] = 0.f;

    for (int ch = 0; ch < D_ / CCH; ++ch) {
        const int cbase = ch * CCH;
        __syncthreads();
        // stage rows l0-1 .. l0+TL (66 rows) x 128 ci
        for (int idx = tid; idx < (TL + 2) * CCH; idx += 256) {
            int r = idx >> 7;
            int c = idx & (CCH - 1);
            int gl = l0 - 1 + r;
            float v = 0.f;
            if (gl >= 0 && gl < L_) v = in[(n * L_ + gl) * D_ + cbase + c];
            xs[r * XROW + c] = v;
        }
        __syncthreads();
#pragma unroll
        for (int k = 0; k < K_; ++k) {
            const float* xrow = &xs[(lane + k) * XROW];
            const float* wk = W + (k * D_ + cbase) * D_ + co_base;
            for (int c4 = 0; c4 < CCH / 4; ++c4) {
                float4 xv = *(const float4*)(xrow + 4 * c4);
                const float* w0 = wk + (4 * c4 + 0) * D_;
                const float* w1 = wk + (4 * c4 + 1) * D_;
                const float* w2 = wk + (4 * c4 + 2) * D_;
                const float* w3 = wk + (4 * c4 + 3) * D_;
#pragma unroll
                for (int j = 0; j < 8; ++j) {
                    acc[j] = fmaf(xv.x, w0[j], acc[j]);
                    acc[j] = fmaf(xv.y, w1[j], acc[j]);
                    acc[j] = fmaf(xv.z, w2[j], acc[j]);
                    acc[j] = fmaf(xv.w, w3[j], acc[j]);
                }
            }
        }
    }
    const int l = l0 + lane;
    float* op = out + ((size_t)(n * L_ + l)) * D_ + co_base;
#pragma unroll
    for (int j = 0; j < 8; ++j) {
        float y = acc[j] + bias[co_base + j];
        op[j] = fmaxf(y, 0.f);
    }
}

// ---------------------------------------------------------------- LN --------
// one wave per row (256 channels = 4 floats/lane), in-place
__global__ __launch_bounds__(256)
void ln_rows_kernel(float* __restrict__ h, const float* __restrict__ g,
                    const float* __restrict__ b) {
    const int row = blockIdx.x * 4 + (threadIdx.x >> 6);
    const int lane = threadIdx.x & 63;
    float* p = h + (size_t)row * D_ + lane * 4;
    float4 v = *(float4*)p;
    float s = v.x + v.y + v.z + v.w;
    float ss = v.x * v.x + v.y * v.y + v.z * v.z + v.w * v.w;
#pragma unroll
    for (int off = 32; off; off >>= 1) {
        s += __shfl_xor(s, off);
        ss += __shfl_xor(ss, off);
    }
    float mu = s * (1.f / D_);
    float var = ss * (1.f / D_) - mu * mu;
    float rs = rsqrtf(var + LN_EPS);
    float4 gv = *(const float4*)&g[lane * 4];
    float4 bv = *(const float4*)&b[lane * 4];
    float4 o;
    o.x = (v.x - mu) * rs * gv.x + bv.x;
    o.y = (v.y - mu) * rs * gv.y + bv.y;
    o.z = (v.z - mu) * rs * gv.z + bv.z;
    o.w = (v.w - mu) * rs * gv.w + bv.w;
    *(float4*)p = o;
}

// LN + fused linear (256 -> 1): log_dur[row] = LN(h[row]) . lin_w + lin_b
__global__ __launch_bounds__(256)
void ln_lin_kernel(const float* __restrict__ h, const float* __restrict__ g,
                   const float* __restrict__ b, const float* __restrict__ lw,
                   const float* __restrict__ lb, float* __restrict__ ld) {
    const int row = blockIdx.x * 4 + (threadIdx.x >> 6);
    const int lane = threadIdx.x & 63;
    const float* p = h + (size_t)row * D_ + lane * 4;
    float4 v = *(const float4*)p;
    float s = v.x + v.y + v.z + v.w;
    float ss = v.x * v.x + v.y * v.y + v.z * v.z + v.w * v.w;
#pragma unroll
    for (int off = 32; off; off >>= 1) {
        s += __shfl_xor(s, off);
        ss += __shfl_xor(ss, off);
    }
    float mu = s * (1.f / D_);
    float var = ss * (1.f / D_) - mu * mu;
    float rs = rsqrtf(var + LN_EPS);
    float4 gv = *(const float4*)&g[lane * 4];
    float4 bv = *(const float4*)&b[lane * 4];
    float4 wv = *(const float4*)&lw[lane * 4];
    float dot = ((v.x - mu) * rs * gv.x + bv.x) * wv.x
              + ((v.y - mu) * rs * gv.y + bv.y) * wv.y
              + ((v.z - mu) * rs * gv.z + bv.z) * wv.z
              + ((v.w - mu) * rs * gv.w + bv.w) * wv.w;
#pragma unroll
    for (int off = 32; off; off >>= 1) dot += __shfl_xor(dot, off);
    if (lane == 0) ld[row] = dot + lb[0];
}

// ---------------------------------------------------------------- gather ----
// out[n,m,:] = x[n, l(m), :] for m < total (l = upper_bound over ends), else 0
__global__ __launch_bounds__(256)
void gather_kernel(const float* __restrict__ x, const int* __restrict__ ends,
                   float* __restrict__ out) {
    __shared__ int es[L_];
    const int n = blockIdx.y;
    const int m0 = blockIdx.x * 64;
    const int tid = threadIdx.x;
    es[tid] = ends[n * L_ + tid];
    es[tid + 256] = ends[n * L_ + tid + 256];
    __syncthreads();
    const int total = es[L_ - 1];
    const int sub = tid >> 6;
    const int lane = tid & 63;
#pragma unroll 4
    for (int i = 0; i < 16; ++i) {
        int m = m0 + i * 4 + sub;
        float4 o = {0.f, 0.f, 0.f, 0.f};
        if (m < total) {
            int lo = -1, hi = L_ - 1;  // first hi with ends[hi] > m
            while (hi - lo > 1) {
                int mid = (lo + hi) >> 1;
                if (es[mid] > m) hi = mid; else lo = mid;
            }
            o = *(const float4*)&x[((size_t)n * L_ + hi) * D_ + lane * 4];
        }
        *(float4*)&out[((size_t)n * M_ + m) * D_ + lane * 4] = o;
    }
}

// ---------------------------------------------------------------- launch ----
extern "C" void kernel_launch(void* const* d_in, const int* in_sizes, int n_in,
                              void* d_out, int out_size, void* d_ws, size_t ws_size,
                              hipStream_t stream) {
    const float* x   = (const float*)d_in[0];
    const float* w1  = (const float*)d_in[1];
    const float* b1  = (const float*)d_in[2];
    const float* g1  = (const float*)d_in[3];
    const float* be1 = (const float*)d_in[4];
    const float* w2  = (const float*)d_in[5];
    const float* b2  = (const float*)d_in[6];
    const float* g2  = (const float*)d_in[7];
    const float* be2 = (const float*)d_in[8];
    const float* lw  = (const float*)d_in[9];
    const float* lb  = (const float*)d_in[10];
    const int* target = (const int*)d_in[11];

    float* out0 = (float*)d_out;                       // [16, 3584, 256]
    float* log_dur = out0 + (size_t)N_ * M_ * D_;      // [16, 512]

    float* h1 = (float*)d_ws;                          // [16, 512, 256]
    float* h2 = h1 + (size_t)N_ * L_ * D_;             // [16, 512, 256]
    int* ends = (int*)(h2 + (size_t)N_ * L_ * D_);     // [16, 512]

    cumsum_kernel<<<N_, L_, 0, stream>>>(target, ends);
    conv_relu_kernel<<<dim3(L_ / TL, CO_SPLIT, N_), 256, 0, stream>>>(x, w1, b1, h1);
    ln_rows_kernel<<<N_ * L_ / 4, 256, 0, stream>>>(h1, g1, be1);
    conv_relu_kernel<<<dim3(L_ / TL, CO_SPLIT, N_), 256, 0, stream>>>(h1, w2, b2, h2);
    ln_lin_kernel<<<N_ * L_ / 4, 256, 0, stream>>>(h2, g2, be2, lw, lb, log_dur);
    gather_kernel<<<dim3(M_ / 64, N_), 256, 0, stream>>>(x, ends, out0);
}

// Round 2
// 90.108 us; speedup vs baseline: 1.9579x; 1.9579x over previous
//
#include <hip/hip_runtime.h>
#include <cstddef>

#define N_ 16
#define L_ 512
#define D_ 256
#define M_ 3584
#define LN_EPS 1e-5f

typedef __attribute__((ext_vector_type(8))) short bf16x8;
typedef __attribute__((ext_vector_type(4))) float f32x4;

__device__ inline unsigned int f2bf_raw(float f) {
    union { float f; unsigned int u; } v; v.f = f;
    return (v.u + 0x7FFFu + ((v.u >> 16) & 1u)) >> 16;   // RNE
}
__device__ inline unsigned int pack2bf(float lo, float hi) {
    return f2bf_raw(lo) | (f2bf_raw(hi) << 16);
}

// ---------------------------------------------------------------- cumsum ----
__global__ void cumsum_kernel(const int* __restrict__ target, int* __restrict__ ends) {
    __shared__ int s[L_];
    int n = blockIdx.x, t = threadIdx.x;
    s[t] = target[n * L_ + t];
    __syncthreads();
    for (int off = 1; off < L_; off <<= 1) {
        int v = (t >= off) ? s[t - off] : 0;
        __syncthreads();
        s[t] += v;
        __syncthreads();
    }
    ends[n * L_ + t] = s[t];
}

// ------------------------------------------------------- weight transpose ---
// W [768 (k= koff*256+ci)][256 co] fp32 -> Wt [256 co][768 k] bf16
__global__ __launch_bounds__(256)
void transpose_w(const float* __restrict__ W, unsigned short* __restrict__ Wt) {
    __shared__ float t[32][33];
    const int kb = blockIdx.x * 32, cb = blockIdx.y * 32;
    const int tx = threadIdx.x & 31, ty = threadIdx.x >> 5;
#pragma unroll
    for (int r = 0; r < 32; r += 8)
        t[ty + r][tx] = W[(size_t)(kb + ty + r) * 256 + cb + tx];
    __syncthreads();
#pragma unroll
    for (int r = 0; r < 32; r += 8)
        Wt[(size_t)(cb + ty + r) * 768 + kb + tx] = (unsigned short)f2bf_raw(t[tx][ty + r]);
}

// ---------------------------------------------------------------- conv ------
// out[row, co] = relu( sum_k im2col(in)[row, k] * Wt[co, k] + bias[co] )
// rows = n*512 + l; k = koff*256 + ci; A row at koff: in[n, l+koff-1, :].
// Tile 64 rows x 128 co, 4 waves each 32x64 (2x4 fragments of 16x16x32 MFMA).
// LDS layout [kquad][row]: lane-consecutive ds_read_b128/ds_write_b128 -> 2-way
// (free) bank aliasing only.
template <bool BF_IN>
__global__ __launch_bounds__(256)
void conv_mfma(const void* __restrict__ in_, const unsigned short* __restrict__ Wt,
               const float* __restrict__ bias, float* __restrict__ out) {
    __shared__ uint4 A4[4][64];    // [k-quad of 8][row]
    __shared__ uint4 B4[4][128];   // [k-quad of 8][co]
    const int row0 = blockIdx.x * 64;
    const int n = row0 >> 9, l0 = row0 & 511;
    const int co0 = blockIdx.y * 128;
    const int tid = threadIdx.x;
    const int lane = tid & 63, wv = tid >> 6;
    const int wr = (wv >> 1) * 32;   // wave's row offset in tile
    const int wc = (wv & 1) * 64;    // wave's co offset in tile
    const int fr = lane & 15, fg = lane >> 4;

    f32x4 acc[2][4];
#pragma unroll
    for (int i = 0; i < 2; ++i)
#pragma unroll
        for (int j = 0; j < 4; ++j) acc[i][j] = (f32x4){0.f, 0.f, 0.f, 0.f};

    for (int ks = 0; ks < 24; ++ks) {
        const int k0 = ks * 32;
        const int koff = k0 >> 8;       // which conv tap (0..2)
        const int ci0 = k0 & 255;       // ci base within tap
        __syncthreads();
        // ---- stage A: wave wv loads k-quad wv, row = lane
        {
            int l = l0 + lane + koff - 1;
            uint4 v = {0u, 0u, 0u, 0u};
            if (l >= 0 && l < L_) {
                if (BF_IN) {
                    v = *(const uint4*)((const unsigned short*)in_ +
                          ((size_t)(n * L_ + l)) * D_ + ci0 + wv * 8);
                } else {
                    const float* p = (const float*)in_ +
                          ((size_t)(n * L_ + l)) * D_ + ci0 + wv * 8;
                    float4 a = *(const float4*)p;
                    float4 b = *(const float4*)(p + 4);
                    v.x = pack2bf(a.x, a.y); v.y = pack2bf(a.z, a.w);
                    v.z = pack2bf(b.x, b.y); v.w = pack2bf(b.z, b.w);
                }
            }
            A4[wv][lane] = v;
        }
        // ---- stage B: 512 slots (4 quads x 128 co), 2 per thread
        for (int s = tid; s < 512; s += 256) {
            int co = s & 127, q = s >> 7;
            B4[q][co] = *(const uint4*)(Wt + (size_t)(co0 + co) * 768 + k0 + q * 8);
        }
        __syncthreads();
        // ---- fragments + MFMA
        bf16x8 av[2], bv[4];
#pragma unroll
        for (int i = 0; i < 2; ++i)
            av[i] = *(const bf16x8*)&A4[fg][wr + i * 16 + fr];
#pragma unroll
        for (int j = 0; j < 4; ++j)
            bv[j] = *(const bf16x8*)&B4[fg][wc + j * 16 + fr];
#pragma unroll
        for (int i = 0; i < 2; ++i)
#pragma unroll
            for (int j = 0; j < 4; ++j)
                acc[i][j] = __builtin_amdgcn_mfma_f32_16x16x32_bf16(
                    av[i], bv[j], acc[i][j], 0, 0, 0);
    }
    // ---- epilogue: D lane mapping col=lane&15, row=(lane>>4)*4+q (m89)
#pragma unroll
    for (int i = 0; i < 2; ++i)
#pragma unroll
        for (int j = 0; j < 4; ++j) {
            int gco = co0 + wc + j * 16 + fr;
            float bs = bias[gco];
#pragma unroll
            for (int q = 0; q < 4; ++q) {
                int grow = row0 + wr + i * 16 + fg * 4 + q;
                out[(size_t)grow * D_ + gco] = fmaxf(acc[i][j][q] + bs, 0.f);
            }
        }
}

// ---------------------------------------------------------------- LN --------
// LN over channels, emit bf16 (input for the next MFMA conv)
__global__ __launch_bounds__(256)
void ln_rows_bf(const float* __restrict__ h, const float* __restrict__ g,
                const float* __restrict__ b, unsigned short* __restrict__ out) {
    const int row = blockIdx.x * 4 + (threadIdx.x >> 6);
    const int lane = threadIdx.x & 63;
    const float* p = h + (size_t)row * D_ + lane * 4;
    float4 v = *(const float4*)p;
    float s = v.x + v.y + v.z + v.w;
    float ss = v.x * v.x + v.y * v.y + v.z * v.z + v.w * v.w;
#pragma unroll
    for (int off = 32; off; off >>= 1) {
        s += __shfl_xor(s, off);
        ss += __shfl_xor(ss, off);
    }
    float mu = s * (1.f / D_);
    float var = ss * (1.f / D_) - mu * mu;
    float rs = rsqrtf(var + LN_EPS);
    float4 gv = *(const float4*)&g[lane * 4];
    float4 bv = *(const float4*)&b[lane * 4];
    ushort4 o;
    o.x = (unsigned short)f2bf_raw((v.x - mu) * rs * gv.x + bv.x);
    o.y = (unsigned short)f2bf_raw((v.y - mu) * rs * gv.y + bv.y);
    o.z = (unsigned short)f2bf_raw((v.z - mu) * rs * gv.z + bv.z);
    o.w = (unsigned short)f2bf_raw((v.w - mu) * rs * gv.w + bv.w);
    *(ushort4*)&out[(size_t)row * D_ + lane * 4] = o;
}

// LN + fused linear (256 -> 1)
__global__ __launch_bounds__(256)
void ln_lin_kernel(const float* __restrict__ h, const float* __restrict__ g,
                   const float* __restrict__ b, const float* __restrict__ lw,
                   const float* __restrict__ lb, float* __restrict__ ld) {
    const int row = blockIdx.x * 4 + (threadIdx.x >> 6);
    const int lane = threadIdx.x & 63;
    const float* p = h + (size_t)row * D_ + lane * 4;
    float4 v = *(const float4*)p;
    float s = v.x + v.y + v.z + v.w;
    float ss = v.x * v.x + v.y * v.y + v.z * v.z + v.w * v.w;
#pragma unroll
    for (int off = 32; off; off >>= 1) {
        s += __shfl_xor(s, off);
        ss += __shfl_xor(ss, off);
    }
    float mu = s * (1.f / D_);
    float var = ss * (1.f / D_) - mu * mu;
    float rs = rsqrtf(var + LN_EPS);
    float4 gv = *(const float4*)&g[lane * 4];
    float4 bv = *(const float4*)&b[lane * 4];
    float4 wv = *(const float4*)&lw[lane * 4];
    float dot = ((v.x - mu) * rs * gv.x + bv.x) * wv.x
              + ((v.y - mu) * rs * gv.y + bv.y) * wv.y
              + ((v.z - mu) * rs * gv.z + bv.z) * wv.z
              + ((v.w - mu) * rs * gv.w + bv.w) * wv.w;
#pragma unroll
    for (int off = 32; off; off >>= 1) dot += __shfl_xor(dot, off);
    if (lane == 0) ld[row] = dot + lb[0];
}

// ---------------------------------------------------------------- gather ----
__global__ __launch_bounds__(256)
void gather_kernel(const float* __restrict__ x, const int* __restrict__ ends,
                   float* __restrict__ out) {
    __shared__ int es[L_];
    const int n = blockIdx.y;
    const int m0 = blockIdx.x * 64;
    const int tid = threadIdx.x;
    es[tid] = ends[n * L_ + tid];
    es[tid + 256] = ends[n * L_ + tid + 256];
    __syncthreads();
    const int total = es[L_ - 1];
    const int sub = tid >> 6;
    const int lane = tid & 63;
#pragma unroll 4
    for (int i = 0; i < 16; ++i) {
        int m = m0 + i * 4 + sub;
        float4 o = {0.f, 0.f, 0.f, 0.f};
        if (m < total) {
            int lo = -1, hi = L_ - 1;  // first hi with ends[hi] > m
            while (hi - lo > 1) {
                int mid = (lo + hi) >> 1;
                if (es[mid] > m) hi = mid; else lo = mid;
            }
            o = *(const float4*)&x[((size_t)n * L_ + hi) * D_ + lane * 4];
        }
        *(float4*)&out[((size_t)n * M_ + m) * D_ + lane * 4] = o;
    }
}

// ---------------------------------------------------------------- launch ----
extern "C" void kernel_launch(void* const* d_in, const int* in_sizes, int n_in,
                              void* d_out, int out_size, void* d_ws, size_t ws_size,
                              hipStream_t stream) {
    const float* x   = (const float*)d_in[0];
    const float* w1  = (const float*)d_in[1];
    const float* b1  = (const float*)d_in[2];
    const float* g1  = (const float*)d_in[3];
    const float* be1 = (const float*)d_in[4];
    const float* w2  = (const float*)d_in[5];
    const float* b2  = (const float*)d_in[6];
    const float* g2  = (const float*)d_in[7];
    const float* be2 = (const float*)d_in[8];
    const float* lw  = (const float*)d_in[9];
    const float* lb  = (const float*)d_in[10];
    const int* target = (const int*)d_in[11];

    float* out0 = (float*)d_out;                       // [16, 3584, 256]
    float* log_dur = out0 + (size_t)N_ * M_ * D_;      // [16, 512]

    const size_t E = (size_t)N_ * L_ * D_;             // 2,097,152
    float* h1 = (float*)d_ws;                          // [E] fp32 (reused as h2)
    unsigned short* h1b = (unsigned short*)(h1 + E);   // [E] bf16
    unsigned short* w1t = h1b + E;                     // [256*768] bf16
    unsigned short* w2t = w1t + 768 * 256;             // [256*768] bf16
    int* ends = (int*)(w2t + 768 * 256);               // [16*512]

    cumsum_kernel<<<N_, L_, 0, stream>>>(target, ends);
    transpose_w<<<dim3(24, 8), 256, 0, stream>>>(w1, w1t);
    transpose_w<<<dim3(24, 8), 256, 0, stream>>>(w2, w2t);

    conv_mfma<false><<<dim3(N_ * L_ / 64, 2), 256, 0, stream>>>(x, w1t, b1, h1);
    ln_rows_bf<<<N_ * L_ / 4, 256, 0, stream>>>(h1, g1, be1, h1b);
    conv_mfma<true><<<dim3(N_ * L_ / 64, 2), 256, 0, stream>>>(h1b, w2t, b2, h1);
    ln_lin_kernel<<<N_ * L_ / 4, 256, 0, stream>>>(h1, g2, be2, lw, lb, log_dur);

    gather_kernel<<<dim3(M_ / 64, N_), 256, 0, stream>>>(x, ends, out0);
}

// Round 3
// 84.230 us; speedup vs baseline: 2.0945x; 1.0698x over previous
//
#include <hip/hip_runtime.h>
#include <cstddef>

#define N_ 16
#define L_ 512
#define D_ 256
#define M_ 3584
#define LN_EPS 1e-5f

typedef __attribute__((ext_vector_type(8))) short bf16x8;
typedef __attribute__((ext_vector_type(4))) float f32x4;

__device__ inline unsigned int f2bf_raw(float f) {
    union { float f; unsigned int u; } v; v.f = f;
    return (v.u + 0x7FFFu + ((v.u >> 16) & 1u)) >> 16;   // RNE
}
__device__ inline unsigned int pack2bf(float lo, float hi) {
    return f2bf_raw(lo) | (f2bf_raw(hi) << 16);
}

// ---------------------------------------------------------------- cumsum ----
__global__ void cumsum_kernel(const int* __restrict__ target, int* __restrict__ ends) {
    __shared__ int s[L_];
    int n = blockIdx.x, t = threadIdx.x;
    s[t] = target[n * L_ + t];
    __syncthreads();
    for (int off = 1; off < L_; off <<= 1) {
        int v = (t >= off) ? s[t - off] : 0;
        __syncthreads();
        s[t] += v;
        __syncthreads();
    }
    ends[n * L_ + t] = s[t];
}

// ------------------------------------------------------- weight transpose ---
// W [768 k][256 co] fp32 -> Wt [256 co][768 k] bf16; blockIdx.z picks layer
__global__ __launch_bounds__(256)
void transpose_w2(const float* __restrict__ W1, unsigned short* __restrict__ Wt1,
                  const float* __restrict__ W2, unsigned short* __restrict__ Wt2) {
    const float* W = blockIdx.z ? W2 : W1;
    unsigned short* Wt = blockIdx.z ? Wt2 : Wt1;
    __shared__ float t[32][33];
    const int kb = blockIdx.x * 32, cb = blockIdx.y * 32;
    const int tx = threadIdx.x & 31, ty = threadIdx.x >> 5;
#pragma unroll
    for (int r = 0; r < 32; r += 8)
        t[ty + r][tx] = W[(size_t)(kb + ty + r) * 256 + cb + tx];
    __syncthreads();
#pragma unroll
    for (int r = 0; r < 32; r += 8)
        Wt[(size_t)(cb + ty + r) * 768 + kb + tx] = (unsigned short)f2bf_raw(t[tx][ty + r]);
}

// ----------------------------------------------------- fused conv+LN(+lin) --
// Tile: 32 rows x 256 co (full channel dim -> LN fusable). 512 thr = 8 waves,
// wave wv: rows (wv>>2)*16..+15, cols (wv&3)*64..+63 => 1x4 frags 16x16x32.
// K = 768 in 24 steps of 32; double-buffered LDS, one barrier per step.
// LDS layout [k-quad][row/co] of uint4: lane-consecutive b128 r/w (free 2-way).
// Epilogue: relu(acc+bias) -> Y LDS tile (aliases staging) -> per-row LN ->
//   FINAL=0: write bf16 rows (input of conv2);  FINAL=1: dot lin_w -> log_dur.
template <bool BF_IN, bool FINAL>
__global__ __launch_bounds__(512)
void conv_ln(const void* __restrict__ in_, const unsigned short* __restrict__ Wt,
             const float* __restrict__ bias, const float* __restrict__ g,
             const float* __restrict__ b, const float* __restrict__ lw,
             const float* __restrict__ lb, void* __restrict__ out_) {
    struct Stage { uint4 A[2][4][32]; uint4 B[2][4][256]; };   // 4KB + 32KB
    __shared__ union SM { Stage st; float Y[32][260]; } sm;    // Y aliases staging

    const int tid = threadIdx.x;
    const int lane = tid & 63, wv = tid >> 6;
    const int row0 = blockIdx.x * 32;
    const int n = row0 >> 9, l0 = row0 & 511;
    const int wr = (wv >> 2) * 16, wc = (wv & 3) * 64;
    const int fr = lane & 15, fg = lane >> 4;

    f32x4 acc[4];
#pragma unroll
    for (int j = 0; j < 4; ++j) acc[j] = (f32x4){0.f, 0.f, 0.f, 0.f};

    const int bq0 = tid >> 8, bco = tid & 255;        // B slot tid  -> quad 0/1
    const int bq1 = bq0 + 2;                          // B slot tid+512 -> quad 2/3
    const int aq = tid >> 5, arow = tid & 31;         // A slot (tid<128)

    uint4 vA, vB0, vB1;
    auto stage_load = [&](int ks) {
        const int koff = ks >> 3, ci0 = (ks & 7) * 32;
        vB0 = *(const uint4*)(Wt + (size_t)bco * 768 + ks * 32 + bq0 * 8);
        vB1 = *(const uint4*)(Wt + (size_t)bco * 768 + ks * 32 + bq1 * 8);
        vA = (uint4){0u, 0u, 0u, 0u};
        if (tid < 128) {
            int l = l0 + arow + koff - 1;
            if (l >= 0 && l < L_) {
                if (BF_IN) {
                    vA = *(const uint4*)((const unsigned short*)in_ +
                          ((size_t)(n * L_ + l)) * D_ + ci0 + aq * 8);
                } else {
                    const float* p = (const float*)in_ +
                          ((size_t)(n * L_ + l)) * D_ + ci0 + aq * 8;
                    float4 x0 = *(const float4*)p;
                    float4 x1 = *(const float4*)(p + 4);
                    vA.x = pack2bf(x0.x, x0.y); vA.y = pack2bf(x0.z, x0.w);
                    vA.z = pack2bf(x1.x, x1.y); vA.w = pack2bf(x1.z, x1.w);
                }
            }
        }
    };
    auto stage_write = [&](int buf) {
        sm.st.B[buf][bq0][bco] = vB0;
        sm.st.B[buf][bq1][bco] = vB1;
        if (tid < 128) sm.st.A[buf][aq][arow] = vA;
    };

    stage_load(0);
    stage_write(0);
    __syncthreads();

    for (int ks = 0; ks < 24; ++ks) {
        const int cur = ks & 1;
        if (ks < 23) stage_load(ks + 1);               // issue early (T14)
        bf16x8 av = *(const bf16x8*)&sm.st.A[cur][fg][wr + fr];
        bf16x8 bv0 = *(const bf16x8*)&sm.st.B[cur][fg][wc + 0 * 16 + fr];
        bf16x8 bv1 = *(const bf16x8*)&sm.st.B[cur][fg][wc + 1 * 16 + fr];
        bf16x8 bv2 = *(const bf16x8*)&sm.st.B[cur][fg][wc + 2 * 16 + fr];
        bf16x8 bv3 = *(const bf16x8*)&sm.st.B[cur][fg][wc + 3 * 16 + fr];
        acc[0] = __builtin_amdgcn_mfma_f32_16x16x32_bf16(av, bv0, acc[0], 0, 0, 0);
        acc[1] = __builtin_amdgcn_mfma_f32_16x16x32_bf16(av, bv1, acc[1], 0, 0, 0);
        acc[2] = __builtin_amdgcn_mfma_f32_16x16x32_bf16(av, bv2, acc[2], 0, 0, 0);
        acc[3] = __builtin_amdgcn_mfma_f32_16x16x32_bf16(av, bv3, acc[3], 0, 0, 0);
        if (ks < 23) stage_write(cur ^ 1);             // write late
        __syncthreads();
    }

    // ---- epilogue: relu(acc+bias) into Y (staging buffers are dead) ----
#pragma unroll
    for (int j = 0; j < 4; ++j) {
        const int co = wc + j * 16 + fr;
        const float bs = bias[co];
#pragma unroll
        for (int q = 0; q < 4; ++q)
            sm.Y[wr + fg * 4 + q][co] = fmaxf(acc[j][q] + bs, 0.f);
    }
    __syncthreads();

    // ---- per-row LayerNorm; wave wv handles rows wv*4..wv*4+3 ----
    const float4 gv = *(const float4*)&g[lane * 4];
    const float4 bvv = *(const float4*)&b[lane * 4];
    float4 lwv = {0.f, 0.f, 0.f, 0.f};
    if (FINAL) lwv = *(const float4*)&lw[lane * 4];
#pragma unroll
    for (int rr = 0; rr < 4; ++rr) {
        const int r = wv * 4 + rr;
        float4 v = *(const float4*)&sm.Y[r][lane * 4];
        float s = v.x + v.y + v.z + v.w;
        float ss = v.x * v.x + v.y * v.y + v.z * v.z + v.w * v.w;
#pragma unroll
        for (int off = 32; off; off >>= 1) {
            s += __shfl_xor(s, off);
            ss += __shfl_xor(ss, off);
        }
        const float mu = s * (1.f / D_);
        const float var = ss * (1.f / D_) - mu * mu;
        const float rs = rsqrtf(var + LN_EPS);
        const float o0 = (v.x - mu) * rs * gv.x + bvv.x;
        const float o1 = (v.y - mu) * rs * gv.y + bvv.y;
        const float o2 = (v.z - mu) * rs * gv.z + bvv.z;
        const float o3 = (v.w - mu) * rs * gv.w + bvv.w;
        if (!FINAL) {
            ushort4 o;
            o.x = (unsigned short)f2bf_raw(o0);
            o.y = (unsigned short)f2bf_raw(o1);
            o.z = (unsigned short)f2bf_raw(o2);
            o.w = (unsigned short)f2bf_raw(o3);
            *(ushort4*)((unsigned short*)out_ + (size_t)(row0 + r) * D_ + lane * 4) = o;
        } else {
            float dot = o0 * lwv.x + o1 * lwv.y + o2 * lwv.z + o3 * lwv.w;
#pragma unroll
            for (int off = 32; off; off >>= 1) dot += __shfl_xor(dot, off);
            if (lane == 0) ((float*)out_)[row0 + r] = dot + lb[0];
        }
    }
}

// ---------------------------------------------------------------- gather ----
__global__ __launch_bounds__(256)
void gather_kernel(const float* __restrict__ x, const int* __restrict__ ends,
                   float* __restrict__ out) {
    __shared__ int es[L_];
    const int n = blockIdx.y;
    const int m0 = blockIdx.x * 64;
    const int tid = threadIdx.x;
    es[tid] = ends[n * L_ + tid];
    es[tid + 256] = ends[n * L_ + tid + 256];
    __syncthreads();
    const int total = es[L_ - 1];
    const int sub = tid >> 6;
    const int lane = tid & 63;
#pragma unroll 4
    for (int i = 0; i < 16; ++i) {
        int m = m0 + i * 4 + sub;
        float4 o = {0.f, 0.f, 0.f, 0.f};
        if (m < total) {
            int lo = -1, hi = L_ - 1;  // first hi with ends[hi] > m
            while (hi - lo > 1) {
                int mid = (lo + hi) >> 1;
                if (es[mid] > m) hi = mid; else lo = mid;
            }
            o = *(const float4*)&x[((size_t)n * L_ + hi) * D_ + lane * 4];
        }
        *(float4*)&out[((size_t)n * M_ + m) * D_ + lane * 4] = o;
    }
}

// ---------------------------------------------------------------- launch ----
extern "C" void kernel_launch(void* const* d_in, const int* in_sizes, int n_in,
                              void* d_out, int out_size, void* d_ws, size_t ws_size,
                              hipStream_t stream) {
    const float* x   = (const float*)d_in[0];
    const float* w1  = (const float*)d_in[1];
    const float* b1  = (const float*)d_in[2];
    const float* g1  = (const float*)d_in[3];
    const float* be1 = (const float*)d_in[4];
    const float* w2  = (const float*)d_in[5];
    const float* b2  = (const float*)d_in[6];
    const float* g2  = (const float*)d_in[7];
    const float* be2 = (const float*)d_in[8];
    const float* lw  = (const float*)d_in[9];
    const float* lb  = (const float*)d_in[10];
    const int* target = (const int*)d_in[11];

    float* out0 = (float*)d_out;                        // [16, 3584, 256]
    float* log_dur = out0 + (size_t)N_ * M_ * D_;       // [16, 512]

    const size_t E = (size_t)N_ * L_ * D_;
    unsigned short* h1b = (unsigned short*)d_ws;        // [E] bf16
    unsigned short* w1t = h1b + E;                      // [256*768] bf16
    unsigned short* w2t = w1t + 768 * 256;              // [256*768] bf16
    int* ends = (int*)(w2t + 768 * 256);                // [16*512]

    cumsum_kernel<<<N_, L_, 0, stream>>>(target, ends);
    transpose_w2<<<dim3(24, 8, 2), 256, 0, stream>>>(w1, w1t, w2, w2t);

    conv_ln<false, false><<<N_ * L_ / 32, 512, 0, stream>>>(
        x, w1t, b1, g1, be1, nullptr, nullptr, h1b);
    conv_ln<true, true><<<N_ * L_ / 32, 512, 0, stream>>>(
        h1b, w2t, b2, g2, be2, lw, lb, log_dur);

    gather_kernel<<<dim3(M_ / 64, N_), 256, 0, stream>>>(x, ends, out0);
}

// Round 4
// 54.663 us; speedup vs baseline: 3.2275x; 1.5409x over previous
//
#include <hip/hip_runtime.h>
#include <cstddef>

#define N_ 16
#define L_ 512
#define D_ 256
#define M_ 3584
#define LN_EPS 1e-5f

typedef __attribute__((ext_vector_type(8))) short bf16x8;
typedef __attribute__((ext_vector_type(4))) float f32x4;

__device__ inline unsigned int f2bf_raw(float f) {
    union { float f; unsigned int u; } v; v.f = f;
    return (v.u + 0x7FFFu + ((v.u >> 16) & 1u)) >> 16;   // RNE
}
__device__ inline unsigned int pack2bf(float lo, float hi) {
    return f2bf_raw(lo) | (f2bf_raw(hi) << 16);
}

// ---------------------------------------------------------------- cumsum ----
__global__ void cumsum_kernel(const int* __restrict__ target, int* __restrict__ ends) {
    __shared__ int s[L_];
    int n = blockIdx.x, t = threadIdx.x;
    s[t] = target[n * L_ + t];
    __syncthreads();
    for (int off = 1; off < L_; off <<= 1) {
        int v = (t >= off) ? s[t - off] : 0;
        __syncthreads();
        s[t] += v;
        __syncthreads();
    }
    ends[n * L_ + t] = s[t];
}

// ------------------------------------------------------- weight transpose ---
// W [768 k][256 co] fp32 -> Wst step-major bf16: [ks=k>>5][co][k&31]
// (so each K-step's 16KB is contiguous -> coalesced staging loads)
__global__ __launch_bounds__(256)
void transpose_w2(const float* __restrict__ W1, unsigned short* __restrict__ Wt1,
                  const float* __restrict__ W2, unsigned short* __restrict__ Wt2) {
    const float* W = blockIdx.z ? W2 : W1;
    unsigned short* Wt = blockIdx.z ? Wt2 : Wt1;
    __shared__ float t[32][33];
    const int kb = blockIdx.x * 32, cb = blockIdx.y * 32;
    const int tx = threadIdx.x & 31, ty = threadIdx.x >> 5;
#pragma unroll
    for (int r = 0; r < 32; r += 8)
        t[ty + r][tx] = W[(size_t)(kb + ty + r) * 256 + cb + tx];
    __syncthreads();
    // element (k = kb+tx, co = cb+ty+r) -> Wst[(kb>>5)*8192 + co*32 + tx]
#pragma unroll
    for (int r = 0; r < 32; r += 8)
        Wt[(size_t)(kb >> 5) * 8192 + (size_t)(cb + ty + r) * 32 + tx] =
            (unsigned short)f2bf_raw(t[tx][ty + r]);
}

// ----------------------------------------------------- fused conv+LN(+lin) --
// Tile: 32 rows x 256 co. 512 thr = 8 waves; wave wv: rows (wv>>2)*16..+15,
// cols (wv&3)*64..+63 (1x4 frags of 16x16x32 MFMA). K = 768 = 24 steps of 32.
// A (34 rows x 256 ci bf16, XOR-swizzled) staged ONCE; B triple-buffered with
// 2-step-ahead coalesced prefetch from step-major Wst; 1 barrier/step.
template <bool BF_IN, bool FINAL>
__global__ __launch_bounds__(512)
void conv_ln(const void* __restrict__ in_, const unsigned short* __restrict__ Wst,
             const float* __restrict__ bias, const float* __restrict__ g,
             const float* __restrict__ b, const float* __restrict__ lw,
             const float* __restrict__ lb, void* __restrict__ out_) {
    __shared__ union SM {
        struct { unsigned char A[34 * 512]; uint4 B[3][4][256]; } st;  // 17408+49152
        float Y[32][260];                                              // epilogue
    } sm;

    const int tid = threadIdx.x;
    const int lane = tid & 63, wv = tid >> 6;
    const int row0 = blockIdx.x * 32;
    const int n = row0 >> 9, l0 = row0 & 511;
    const int wr = (wv >> 2) * 16, wc = (wv & 3) * 64;
    const int fr = lane & 15, fg = lane >> 4;

    f32x4 acc[4];
#pragma unroll
    for (int j = 0; j < 4; ++j) acc[j] = (f32x4){0.f, 0.f, 0.f, 0.f};

    // ---- stage A once: rows r=0..33 <-> l = l0-1+r, bf16, XOR-swizzled ----
    if (BF_IN) {
        for (int idx = tid; idx < 34 * 32; idx += 512) {      // 16B chunks
            int r = idx >> 5, q = idx & 31;
            int l = l0 - 1 + r;
            uint4 v = {0u, 0u, 0u, 0u};
            if (l >= 0 && l < L_)
                v = ((const uint4*)((const unsigned short*)in_ +
                      ((size_t)(n * L_ + l)) * D_))[q];
            int colb = q * 16;
            *(uint4*)(sm.st.A + r * 512 + (colb ^ ((r & 7) << 4))) = v;
        }
    } else {
        for (int idx = tid; idx < 34 * 64; idx += 512) {      // float4 chunks
            int r = idx >> 6, c4 = idx & 63;
            int l = l0 - 1 + r;
            float4 v = {0.f, 0.f, 0.f, 0.f};
            if (l >= 0 && l < L_)
                v = ((const float4*)((const float*)in_ +
                      ((size_t)(n * L_ + l)) * D_))[c4];
            uint2 p;
            p.x = pack2bf(v.x, v.y);
            p.y = pack2bf(v.z, v.w);
            int colb = c4 * 8;
            *(uint2*)(sm.st.A + r * 512 +
                      (((colb & 0x1F0) ^ ((r & 7) << 4)) | (colb & 0xF))) = p;
        }
    }

    // ---- B staging helpers: step ks chunk = Wst + ks*8192 (16KB, contiguous)
    const int bco = tid >> 1;                 // co row this thread stages
    const int bq0 = (tid & 1) * 2;            // quads bq0, bq0+1
    const unsigned short* wbase = Wst + (size_t)bco * 32 + (tid & 1) * 16;

    uint4 c0, c1, n0, n1;
    c0 = *(const uint4*)(wbase);              // ks=0
    c1 = *(const uint4*)(wbase + 8);
    n0 = *(const uint4*)(wbase + 8192);       // ks=1
    n1 = *(const uint4*)(wbase + 8192 + 8);
    sm.st.B[0][bq0][bco] = c0;
    sm.st.B[0][bq0 + 1][bco] = c1;
    c0 = n0; c1 = n1;
    __syncthreads();

    int rb = 0;                               // read buffer = ks%3
    for (int ks = 0; ks < 24; ++ks) {
        if (ks < 22) {                        // issue loads for ks+2
            const unsigned short* wp = wbase + (size_t)(ks + 2) * 8192;
            n0 = *(const uint4*)(wp);
            n1 = *(const uint4*)(wp + 8);
        }
        const int koff = ks >> 3;
        const int ci0b = (ks & 7) * 64;       // byte col base in A row
        const int ar = wr + fr + koff;        // A row (l - l0 + 1)
        const int acol = (ci0b + fg * 16) ^ ((ar & 7) << 4);
        bf16x8 av = *(const bf16x8*)(sm.st.A + ar * 512 + acol);
        bf16x8 bv0 = *(const bf16x8*)&sm.st.B[rb][fg][wc + 0 * 16 + fr];
        bf16x8 bv1 = *(const bf16x8*)&sm.st.B[rb][fg][wc + 1 * 16 + fr];
        bf16x8 bv2 = *(const bf16x8*)&sm.st.B[rb][fg][wc + 2 * 16 + fr];
        bf16x8 bv3 = *(const bf16x8*)&sm.st.B[rb][fg][wc + 3 * 16 + fr];
        acc[0] = __builtin_amdgcn_mfma_f32_16x16x32_bf16(av, bv0, acc[0], 0, 0, 0);
        acc[1] = __builtin_amdgcn_mfma_f32_16x16x32_bf16(av, bv1, acc[1], 0, 0, 0);
        acc[2] = __builtin_amdgcn_mfma_f32_16x16x32_bf16(av, bv2, acc[2], 0, 0, 0);
        acc[3] = __builtin_amdgcn_mfma_f32_16x16x32_bf16(av, bv3, acc[3], 0, 0, 0);
        if (ks < 23) {                        // write ks+1's data (held in regs)
            int wb = rb + 1; if (wb == 3) wb = 0;
            sm.st.B[wb][bq0][bco] = c0;
            sm.st.B[wb][bq0 + 1][bco] = c1;
        }
        c0 = n0; c1 = n1;
        rb = rb + 1; if (rb == 3) rb = 0;
        __syncthreads();
    }

    // ---- epilogue: relu(acc+bias) into Y (aliases staging; all dead) ----
#pragma unroll
    for (int j = 0; j < 4; ++j) {
        const int co = wc + j * 16 + fr;
        const float bs = bias[co];
#pragma unroll
        for (int q = 0; q < 4; ++q)
            sm.Y[wr + fg * 4 + q][co] = fmaxf(acc[j][q] + bs, 0.f);
    }
    __syncthreads();

    // ---- per-row LayerNorm; wave wv handles rows wv*4..wv*4+3 ----
    const float4 gv = *(const float4*)&g[lane * 4];
    const float4 bvv = *(const float4*)&b[lane * 4];
    float4 lwv = {0.f, 0.f, 0.f, 0.f};
    if (FINAL) lwv = *(const float4*)&lw[lane * 4];
#pragma unroll
    for (int rr = 0; rr < 4; ++rr) {
        const int r = wv * 4 + rr;
        float4 v = *(const float4*)&sm.Y[r][lane * 4];
        float s = v.x + v.y + v.z + v.w;
        float ss = v.x * v.x + v.y * v.y + v.z * v.z + v.w * v.w;
#pragma unroll
        for (int off = 32; off; off >>= 1) {
            s += __shfl_xor(s, off);
            ss += __shfl_xor(ss, off);
        }
        const float mu = s * (1.f / D_);
        const float var = ss * (1.f / D_) - mu * mu;
        const float rs = rsqrtf(var + LN_EPS);
        const float o0 = (v.x - mu) * rs * gv.x + bvv.x;
        const float o1 = (v.y - mu) * rs * gv.y + bvv.y;
        const float o2 = (v.z - mu) * rs * gv.z + bvv.z;
        const float o3 = (v.w - mu) * rs * gv.w + bvv.w;
        if (!FINAL) {
            ushort4 o;
            o.x = (unsigned short)f2bf_raw(o0);
            o.y = (unsigned short)f2bf_raw(o1);
            o.z = (unsigned short)f2bf_raw(o2);
            o.w = (unsigned short)f2bf_raw(o3);
            *(ushort4*)((unsigned short*)out_ + (size_t)(row0 + r) * D_ + lane * 4) = o;
        } else {
            float dot = o0 * lwv.x + o1 * lwv.y + o2 * lwv.z + o3 * lwv.w;
#pragma unroll
            for (int off = 32; off; off >>= 1) dot += __shfl_xor(dot, off);
            if (lane == 0) ((float*)out_)[row0 + r] = dot + lb[0];
        }
    }
}

// ---------------------------------------------------------------- gather ----
__global__ __launch_bounds__(256)
void gather_kernel(const float* __restrict__ x, const int* __restrict__ ends,
                   float* __restrict__ out) {
    __shared__ int es[L_];
    const int n = blockIdx.y;
    const int m0 = blockIdx.x * 64;
    const int tid = threadIdx.x;
    es[tid] = ends[n * L_ + tid];
    es[tid + 256] = ends[n * L_ + tid + 256];
    __syncthreads();
    const int total = es[L_ - 1];
    const int sub = tid >> 6;
    const int lane = tid & 63;
#pragma unroll 4
    for (int i = 0; i < 16; ++i) {
        int m = m0 + i * 4 + sub;
        float4 o = {0.f, 0.f, 0.f, 0.f};
        if (m < total) {
            int lo = -1, hi = L_ - 1;  // first hi with ends[hi] > m
            while (hi - lo > 1) {
                int mid = (lo + hi) >> 1;
                if (es[mid] > m) hi = mid; else lo = mid;
            }
            o = *(const float4*)&x[((size_t)n * L_ + hi) * D_ + lane * 4];
        }
        *(float4*)&out[((size_t)n * M_ + m) * D_ + lane * 4] = o;
    }
}

// ---------------------------------------------------------------- launch ----
extern "C" void kernel_launch(void* const* d_in, const int* in_sizes, int n_in,
                              void* d_out, int out_size, void* d_ws, size_t ws_size,
                              hipStream_t stream) {
    const float* x   = (const float*)d_in[0];
    const float* w1  = (const float*)d_in[1];
    const float* b1  = (const float*)d_in[2];
    const float* g1  = (const float*)d_in[3];
    const float* be1 = (const float*)d_in[4];
    const float* w2  = (const float*)d_in[5];
    const float* b2  = (const float*)d_in[6];
    const float* g2  = (const float*)d_in[7];
    const float* be2 = (const float*)d_in[8];
    const float* lw  = (const float*)d_in[9];
    const float* lb  = (const float*)d_in[10];
    const int* target = (const int*)d_in[11];

    float* out0 = (float*)d_out;                        // [16, 3584, 256]
    float* log_dur = out0 + (size_t)N_ * M_ * D_;       // [16, 512]

    const size_t E = (size_t)N_ * L_ * D_;
    unsigned short* h1b = (unsigned short*)d_ws;        // [E] bf16
    unsigned short* w1t = h1b + E;                      // [24*8192] bf16
    unsigned short* w2t = w1t + 24 * 8192;              // [24*8192] bf16
    int* ends = (int*)(w2t + 24 * 8192);                // [16*512]

    cumsum_kernel<<<N_, L_, 0, stream>>>(target, ends);
    transpose_w2<<<dim3(24, 8, 2), 256, 0, stream>>>(w1, w1t, w2, w2t);

    conv_ln<false, false><<<N_ * L_ / 32, 512, 0, stream>>>(
        x, w1t, b1, g1, be1, nullptr, nullptr, h1b);
    conv_ln<true, true><<<N_ * L_ / 32, 512, 0, stream>>>(
        h1b, w2t, b2, g2, be2, lw, lb, log_dur);

    gather_kernel<<<dim3(M_ / 64, N_), 256, 0, stream>>>(x, ends, out0);
}

// Round 5
// 52.731 us; speedup vs baseline: 3.3457x; 1.0366x over previous
//
#include <hip/hip_runtime.h>
#include <cstddef>

#define N_ 16
#define L_ 512
#define D_ 256
#define M_ 3584
#define LN_EPS 1e-5f

typedef __attribute__((ext_vector_type(8))) short bf16x8;
typedef __attribute__((ext_vector_type(4))) float f32x4;

__device__ inline unsigned int f2bf_raw(float f) {
    union { float f; unsigned int u; } v; v.f = f;
    return (v.u + 0x7FFFu + ((v.u >> 16) & 1u)) >> 16;   // RNE
}
__device__ inline unsigned int pack2bf(float lo, float hi) {
    return f2bf_raw(lo) | (f2bf_raw(hi) << 16);
}

// ------------------------------------------------------------------ prep ----
// blocks 0..191: two 32x32 weight-transpose tiles each (fp32 W -> step-major
//   bf16 Wst[ks][co][k&31]); blocks 192..207: per-n cumsum of target.
__global__ __launch_bounds__(512)
void prep_kernel(const float* __restrict__ W1, unsigned short* __restrict__ Wt1,
                 const float* __restrict__ W2, unsigned short* __restrict__ Wt2,
                 const int* __restrict__ target, int* __restrict__ ends) {
    __shared__ union { float t[2][32][33]; int s[L_]; } sm;
    const int bid = blockIdx.x;
    if (bid < 192) {
        const int half = threadIdx.x >> 8, st = threadIdx.x & 255;
        const int t = bid * 2 + half;                 // tile id 0..383
        const int kb = (t % 24) * 32;
        const int cb = ((t / 24) % 8) * 32;
        const float* W = (t >= 192) ? W2 : W1;
        unsigned short* Wt = (t >= 192) ? Wt2 : Wt1;
        const int tx = st & 31, ty = st >> 5;
#pragma unroll
        for (int r = 0; r < 32; r += 8)
            sm.t[half][ty + r][tx] = W[(size_t)(kb + ty + r) * 256 + cb + tx];
        __syncthreads();
#pragma unroll
        for (int r = 0; r < 32; r += 8)
            Wt[(size_t)(kb >> 5) * 8192 + (size_t)(cb + ty + r) * 32 + tx] =
                (unsigned short)f2bf_raw(sm.t[half][tx][ty + r]);
    } else {
        const int n = bid - 192, t = threadIdx.x;
        sm.s[t] = target[n * L_ + t];
        __syncthreads();
        for (int off = 1; off < L_; off <<= 1) {
            int v = (t >= off) ? sm.s[t - off] : 0;
            __syncthreads();
            sm.s[t] += v;
            __syncthreads();
        }
        ends[n * L_ + t] = sm.s[t];
    }
}

// ---------------------------------------- fused conv+LN(+lin)  ||  gather ---
// blocks [0,256): conv tile 32 rows x 256 co (8 waves, 1x4 frags 16x16x32).
//   A (34x256 bf16, XOR-swizzled) staged once; B triple-buffered, 2-step
//   prefetch from step-major Wst; 1 barrier/step; fused LN (+linear if FINAL).
// blocks [256,480): gather of 128 mel rows each, m in [m_off, m_off+1792).
template <bool BF_IN, bool FINAL>
__global__ __launch_bounds__(512, 2)
void conv_gather(const void* __restrict__ in_, const unsigned short* __restrict__ Wst,
                 const float* __restrict__ bias, const float* __restrict__ g,
                 const float* __restrict__ b, const float* __restrict__ lw,
                 const float* __restrict__ lb, void* __restrict__ out_,
                 const float* __restrict__ x, const int* __restrict__ ends,
                 float* __restrict__ out0, int m_off) {
    __shared__ union SM {
        struct { unsigned char A[34 * 512]; uint4 B[3][4][256]; } st;  // 66560 B
        float Y[32][260];
        int es[L_];
    } sm;

    const int tid = threadIdx.x;
    const int lane = tid & 63, wv = tid >> 6;

    if (blockIdx.x >= 256) {
        // ------------------------------ gather role ------------------------
        const int gb = blockIdx.x - 256;        // 0..223
        const int n = gb / 14;
        const int m0 = m_off + (gb % 14) * 128;
        sm.es[tid] = ends[n * L_ + tid];
        __syncthreads();
        const int total = sm.es[L_ - 1];
#pragma unroll 4
        for (int i = 0; i < 16; ++i) {
            int m = m0 + i * 8 + wv;
            float4 o = {0.f, 0.f, 0.f, 0.f};
            if (m < total) {
                int lo = -1, hi = L_ - 1;       // first hi with es[hi] > m
                while (hi - lo > 1) {
                    int mid = (lo + hi) >> 1;
                    if (sm.es[mid] > m) hi = mid; else lo = mid;
                }
                o = *(const float4*)&x[((size_t)n * L_ + hi) * D_ + lane * 4];
            }
            *(float4*)&out0[((size_t)n * M_ + m) * D_ + lane * 4] = o;
        }
        return;
    }

    // ---------------------------------- conv role --------------------------
    const int row0 = blockIdx.x * 32;
    const int n = row0 >> 9, l0 = row0 & 511;
    const int wr = (wv >> 2) * 16, wc = (wv & 3) * 64;
    const int fr = lane & 15, fg = lane >> 4;

    f32x4 acc[4];
#pragma unroll
    for (int j = 0; j < 4; ++j) acc[j] = (f32x4){0.f, 0.f, 0.f, 0.f};

    // ---- stage A once: rows r=0..33 <-> l = l0-1+r, bf16, XOR-swizzled ----
    if (BF_IN) {
        for (int idx = tid; idx < 34 * 32; idx += 512) {      // 16B chunks
            int r = idx >> 5, q = idx & 31;
            int l = l0 - 1 + r;
            uint4 v = {0u, 0u, 0u, 0u};
            if (l >= 0 && l < L_)
                v = ((const uint4*)((const unsigned short*)in_ +
                      ((size_t)(n * L_ + l)) * D_))[q];
            int colb = q * 16;
            *(uint4*)(sm.st.A + r * 512 + (colb ^ ((r & 7) << 4))) = v;
        }
    } else {
        for (int idx = tid; idx < 34 * 64; idx += 512) {      // float4 chunks
            int r = idx >> 6, c4 = idx & 63;
            int l = l0 - 1 + r;
            float4 v = {0.f, 0.f, 0.f, 0.f};
            if (l >= 0 && l < L_)
                v = ((const float4*)((const float*)in_ +
                      ((size_t)(n * L_ + l)) * D_))[c4];
            uint2 p;
            p.x = pack2bf(v.x, v.y);
            p.y = pack2bf(v.z, v.w);
            int colb = c4 * 8;
            *(uint2*)(sm.st.A + r * 512 +
                      (((colb & 0x1F0) ^ ((r & 7) << 4)) | (colb & 0xF))) = p;
        }
    }

    // ---- B staging: step ks chunk = Wst + ks*8192 (16KB, contiguous) ----
    const int bco = tid >> 1;
    const int bq0 = (tid & 1) * 2;
    const unsigned short* wbase = Wst + (size_t)bco * 32 + (tid & 1) * 16;

    uint4 c0, c1, n0, n1;
    c0 = *(const uint4*)(wbase);
    c1 = *(const uint4*)(wbase + 8);
    n0 = *(const uint4*)(wbase + 8192);
    n1 = *(const uint4*)(wbase + 8192 + 8);
    sm.st.B[0][bq0][bco] = c0;
    sm.st.B[0][bq0 + 1][bco] = c1;
    c0 = n0; c1 = n1;
    __syncthreads();

    int rb = 0;
    for (int ks = 0; ks < 24; ++ks) {
        if (ks < 22) {
            const unsigned short* wp = wbase + (size_t)(ks + 2) * 8192;
            n0 = *(const uint4*)(wp);
            n1 = *(const uint4*)(wp + 8);
        }
        const int koff = ks >> 3;
        const int ci0b = (ks & 7) * 64;
        const int ar = wr + fr + koff;
        const int acol = (ci0b + fg * 16) ^ ((ar & 7) << 4);
        bf16x8 av = *(const bf16x8*)(sm.st.A + ar * 512 + acol);
        bf16x8 bv0 = *(const bf16x8*)&sm.st.B[rb][fg][wc + 0 * 16 + fr];
        bf16x8 bv1 = *(const bf16x8*)&sm.st.B[rb][fg][wc + 1 * 16 + fr];
        bf16x8 bv2 = *(const bf16x8*)&sm.st.B[rb][fg][wc + 2 * 16 + fr];
        bf16x8 bv3 = *(const bf16x8*)&sm.st.B[rb][fg][wc + 3 * 16 + fr];
        acc[0] = __builtin_amdgcn_mfma_f32_16x16x32_bf16(av, bv0, acc[0], 0, 0, 0);
        acc[1] = __builtin_amdgcn_mfma_f32_16x16x32_bf16(av, bv1, acc[1], 0, 0, 0);
        acc[2] = __builtin_amdgcn_mfma_f32_16x16x32_bf16(av, bv2, acc[2], 0, 0, 0);
        acc[3] = __builtin_amdgcn_mfma_f32_16x16x32_bf16(av, bv3, acc[3], 0, 0, 0);
        if (ks < 23) {
            int wb = rb + 1; if (wb == 3) wb = 0;
            sm.st.B[wb][bq0][bco] = c0;
            sm.st.B[wb][bq0 + 1][bco] = c1;
        }
        c0 = n0; c1 = n1;
        rb = rb + 1; if (rb == 3) rb = 0;
        __syncthreads();
    }

    // ---- epilogue: relu(acc+bias) into Y (staging dead) ----
#pragma unroll
    for (int j = 0; j < 4; ++j) {
        const int co = wc + j * 16 + fr;
        const float bs = bias[co];
#pragma unroll
        for (int q = 0; q < 4; ++q)
            sm.Y[wr + fg * 4 + q][co] = fmaxf(acc[j][q] + bs, 0.f);
    }
    __syncthreads();

    // ---- per-row LayerNorm; wave wv handles rows wv*4..wv*4+3 ----
    const float4 gv = *(const float4*)&g[lane * 4];
    const float4 bvv = *(const float4*)&b[lane * 4];
    float4 lwv = {0.f, 0.f, 0.f, 0.f};
    if (FINAL) lwv = *(const float4*)&lw[lane * 4];
#pragma unroll
    for (int rr = 0; rr < 4; ++rr) {
        const int r = wv * 4 + rr;
        float4 v = *(const float4*)&sm.Y[r][lane * 4];
        float s = v.x + v.y + v.z + v.w;
        float ss = v.x * v.x + v.y * v.y + v.z * v.z + v.w * v.w;
#pragma unroll
        for (int off = 32; off; off >>= 1) {
            s += __shfl_xor(s, off);
            ss += __shfl_xor(ss, off);
        }
        const float mu = s * (1.f / D_);
        const float var = ss * (1.f / D_) - mu * mu;
        const float rs = rsqrtf(var + LN_EPS);
        const float o0 = (v.x - mu) * rs * gv.x + bvv.x;
        const float o1 = (v.y - mu) * rs * gv.y + bvv.y;
        const float o2 = (v.z - mu) * rs * gv.z + bvv.z;
        const float o3 = (v.w - mu) * rs * gv.w + bvv.w;
        if (!FINAL) {
            ushort4 o;
            o.x = (unsigned short)f2bf_raw(o0);
            o.y = (unsigned short)f2bf_raw(o1);
            o.z = (unsigned short)f2bf_raw(o2);
            o.w = (unsigned short)f2bf_raw(o3);
            *(ushort4*)((unsigned short*)out_ + (size_t)(row0 + r) * D_ + lane * 4) = o;
        } else {
            float dot = o0 * lwv.x + o1 * lwv.y + o2 * lwv.z + o3 * lwv.w;
#pragma unroll
            for (int off = 32; off; off >>= 1) dot += __shfl_xor(dot, off);
            if (lane == 0) ((float*)out_)[row0 + r] = dot + lb[0];
        }
    }
}

// ---------------------------------------------------------------- launch ----
extern "C" void kernel_launch(void* const* d_in, const int* in_sizes, int n_in,
                              void* d_out, int out_size, void* d_ws, size_t ws_size,
                              hipStream_t stream) {
    const float* x   = (const float*)d_in[0];
    const float* w1  = (const float*)d_in[1];
    const float* b1  = (const float*)d_in[2];
    const float* g1  = (const float*)d_in[3];
    const float* be1 = (const float*)d_in[4];
    const float* w2  = (const float*)d_in[5];
    const float* b2  = (const float*)d_in[6];
    const float* g2  = (const float*)d_in[7];
    const float* be2 = (const float*)d_in[8];
    const float* lw  = (const float*)d_in[9];
    const float* lb  = (const float*)d_in[10];
    const int* target = (const int*)d_in[11];

    float* out0 = (float*)d_out;                        // [16, 3584, 256]
    float* log_dur = out0 + (size_t)N_ * M_ * D_;       // [16, 512]

    const size_t E = (size_t)N_ * L_ * D_;
    unsigned short* h1b = (unsigned short*)d_ws;        // [E] bf16
    unsigned short* w1t = h1b + E;                      // [24*8192] bf16
    unsigned short* w2t = w1t + 24 * 8192;              // [24*8192] bf16
    int* ends = (int*)(w2t + 24 * 8192);                // [16*512]

    prep_kernel<<<208, 512, 0, stream>>>(w1, w1t, w2, w2t, target, ends);
    conv_gather<false, false><<<480, 512, 0, stream>>>(
        x, w1t, b1, g1, be1, nullptr, nullptr, h1b, x, ends, out0, 0);
    conv_gather<true, true><<<480, 512, 0, stream>>>(
        h1b, w2t, b2, g2, be2, lw, lb, log_dur, x, ends, out0, M_ / 2);
}

// Round 6
// 44.884 us; speedup vs baseline: 3.9306x; 1.1748x over previous
//
#include <hip/hip_runtime.h>
#include <cstddef>

#define N_ 16
#define L_ 512
#define D_ 256
#define M_ 3584
#define LN_EPS 1e-5f

typedef __attribute__((ext_vector_type(8))) short bf16x8;
typedef __attribute__((ext_vector_type(4))) float f32x4;

__device__ inline unsigned int f2bf_raw(float f) {
    union { float f; unsigned int u; } v; v.f = f;
    return (v.u + 0x7FFFu + ((v.u >> 16) & 1u)) >> 16;   // RNE
}
__device__ inline unsigned int pack2bf(float lo, float hi) {
    return f2bf_raw(lo) | (f2bf_raw(hi) << 16);
}

// Publish barrier: wait own LDS ops, then barrier — does NOT drain vmcnt,
// so global prefetch loads stay in flight across K-steps (T4).
__device__ inline void barrier_lgkm() {
    asm volatile("s_waitcnt lgkmcnt(0)" ::: "memory");
    __builtin_amdgcn_s_barrier();
}

// ------------------------------------------------------------------ prep ----
// blocks 0..191: two 32x32 weight-transpose tiles each (fp32 W -> step-major
//   bf16 Wst[ks][co][k&31]); blocks 192..207: per-n cumsum of target.
__global__ __launch_bounds__(512)
void prep_kernel(const float* __restrict__ W1, unsigned short* __restrict__ Wt1,
                 const float* __restrict__ W2, unsigned short* __restrict__ Wt2,
                 const int* __restrict__ target, int* __restrict__ ends) {
    __shared__ union { float t[2][32][33]; int s[L_]; } sm;
    const int bid = blockIdx.x;
    if (bid < 192) {
        const int half = threadIdx.x >> 8, st = threadIdx.x & 255;
        const int t = bid * 2 + half;                 // tile id 0..383
        const int kb = (t % 24) * 32;
        const int cb = ((t / 24) % 8) * 32;
        const float* W = (t >= 192) ? W2 : W1;
        unsigned short* Wt = (t >= 192) ? Wt2 : Wt1;
        const int tx = st & 31, ty = st >> 5;
#pragma unroll
        for (int r = 0; r < 32; r += 8)
            sm.t[half][ty + r][tx] = W[(size_t)(kb + ty + r) * 256 + cb + tx];
        __syncthreads();
#pragma unroll
        for (int r = 0; r < 32; r += 8)
            Wt[(size_t)(kb >> 5) * 8192 + (size_t)(cb + ty + r) * 32 + tx] =
                (unsigned short)f2bf_raw(sm.t[half][tx][ty + r]);
    } else {
        const int n = bid - 192, t = threadIdx.x;
        sm.s[t] = target[n * L_ + t];
        __syncthreads();
        for (int off = 1; off < L_; off <<= 1) {
            int v = (t >= off) ? sm.s[t - off] : 0;
            __syncthreads();
            sm.s[t] += v;
            __syncthreads();
        }
        ends[n * L_ + t] = sm.s[t];
    }
}

// ---------------------------------------- fused conv+LN(+lin)  ||  gather ---
// Grid 512, 2 blocks/CU co-resident (launch_bounds(512,4) => 4 waves/EU).
// blocks [0,256): conv tile 32 rows x 256 co (8 waves, 1x4 frags 16x16x32).
//   A (34x256 bf16, XOR-swizzled) staged once; B triple-buffered, 2-step
//   prefetch from step-major Wst; lgkm-only barrier per step (prefetch lives).
// blocks [256,512): gather of 112 mel rows each, m in [m_off, m_off+1792).
template <bool BF_IN, bool FINAL>
__global__ __launch_bounds__(512, 4)
void conv_gather(const void* __restrict__ in_, const unsigned short* __restrict__ Wst,
                 const float* __restrict__ bias, const float* __restrict__ g,
                 const float* __restrict__ b, const float* __restrict__ lw,
                 const float* __restrict__ lb, void* __restrict__ out_,
                 const float* __restrict__ x, const int* __restrict__ ends,
                 float* __restrict__ out0, int m_off) {
    __shared__ union SM {
        struct { unsigned char A[34 * 512]; uint4 B[3][4][256]; } st;  // 66560 B
        float Y[32][260];
        int es[L_];
    } sm;

    const int tid = threadIdx.x;
    const int lane = tid & 63, wv = tid >> 6;

    if (blockIdx.x >= 256) {
        // ------------------------------ gather role ------------------------
        const int gb = blockIdx.x - 256;        // 0..255
        const int n = gb >> 4;
        const int m0 = m_off + (gb & 15) * 112;
        sm.es[tid] = ends[n * L_ + tid];
        __syncthreads();
        const int total = sm.es[L_ - 1];
#pragma unroll 2
        for (int i = 0; i < 14; ++i) {
            int m = m0 + i * 8 + wv;
            float4 o = {0.f, 0.f, 0.f, 0.f};
            if (m < total) {
                int lo = -1, hi = L_ - 1;       // first hi with es[hi] > m
                while (hi - lo > 1) {
                    int mid = (lo + hi) >> 1;
                    if (sm.es[mid] > m) hi = mid; else lo = mid;
                }
                o = *(const float4*)&x[((size_t)n * L_ + hi) * D_ + lane * 4];
            }
            *(float4*)&out0[((size_t)n * M_ + m) * D_ + lane * 4] = o;
        }
        return;
    }

    // ---------------------------------- conv role --------------------------
    const int row0 = blockIdx.x * 32;
    const int n = row0 >> 9, l0 = row0 & 511;
    const int wr = (wv >> 2) * 16, wc = (wv & 3) * 64;
    const int fr = lane & 15, fg = lane >> 4;

    f32x4 acc[4];
#pragma unroll
    for (int j = 0; j < 4; ++j) acc[j] = (f32x4){0.f, 0.f, 0.f, 0.f};

    // ---- stage A once: rows r=0..33 <-> l = l0-1+r, bf16, XOR-swizzled ----
    if (BF_IN) {
        for (int idx = tid; idx < 34 * 32; idx += 512) {      // 16B chunks
            int r = idx >> 5, q = idx & 31;
            int l = l0 - 1 + r;
            uint4 v = {0u, 0u, 0u, 0u};
            if (l >= 0 && l < L_)
                v = ((const uint4*)((const unsigned short*)in_ +
                      ((size_t)(n * L_ + l)) * D_))[q];
            int colb = q * 16;
            *(uint4*)(sm.st.A + r * 512 + (colb ^ ((r & 7) << 4))) = v;
        }
    } else {
        for (int idx = tid; idx < 34 * 64; idx += 512) {      // float4 chunks
            int r = idx >> 6, c4 = idx & 63;
            int l = l0 - 1 + r;
            float4 v = {0.f, 0.f, 0.f, 0.f};
            if (l >= 0 && l < L_)
                v = ((const float4*)((const float*)in_ +
                      ((size_t)(n * L_ + l)) * D_))[c4];
            uint2 p;
            p.x = pack2bf(v.x, v.y);
            p.y = pack2bf(v.z, v.w);
            int colb = c4 * 8;
            *(uint2*)(sm.st.A + r * 512 +
                      (((colb & 0x1F0) ^ ((r & 7) << 4)) | (colb & 0xF))) = p;
        }
    }

    // ---- B staging: step ks chunk = Wst + ks*8192 (16KB, contiguous) ----
    const int bco = tid >> 1;
    const int bq0 = (tid & 1) * 2;
    const unsigned short* wbase = Wst + (size_t)bco * 32 + (tid & 1) * 16;

    uint4 c0, c1, n0, n1;
    c0 = *(const uint4*)(wbase);
    c1 = *(const uint4*)(wbase + 8);
    n0 = *(const uint4*)(wbase + 8192);
    n1 = *(const uint4*)(wbase + 8192 + 8);
    sm.st.B[0][bq0][bco] = c0;
    sm.st.B[0][bq0 + 1][bco] = c1;
    c0 = n0; c1 = n1;
    barrier_lgkm();

    int rb = 0;
    for (int ks = 0; ks < 24; ++ks) {
        if (ks < 22) {
            const unsigned short* wp = wbase + (size_t)(ks + 2) * 8192;
            n0 = *(const uint4*)(wp);
            n1 = *(const uint4*)(wp + 8);
        }
        const int koff = ks >> 3;
        const int ci0b = (ks & 7) * 64;
        const int ar = wr + fr + koff;
        const int acol = (ci0b + fg * 16) ^ ((ar & 7) << 4);
        bf16x8 av = *(const bf16x8*)(sm.st.A + ar * 512 + acol);
        bf16x8 bv0 = *(const bf16x8*)&sm.st.B[rb][fg][wc + 0 * 16 + fr];
        bf16x8 bv1 = *(const bf16x8*)&sm.st.B[rb][fg][wc + 1 * 16 + fr];
        bf16x8 bv2 = *(const bf16x8*)&sm.st.B[rb][fg][wc + 2 * 16 + fr];
        bf16x8 bv3 = *(const bf16x8*)&sm.st.B[rb][fg][wc + 3 * 16 + fr];
        acc[0] = __builtin_amdgcn_mfma_f32_16x16x32_bf16(av, bv0, acc[0], 0, 0, 0);
        acc[1] = __builtin_amdgcn_mfma_f32_16x16x32_bf16(av, bv1, acc[1], 0, 0, 0);
        acc[2] = __builtin_amdgcn_mfma_f32_16x16x32_bf16(av, bv2, acc[2], 0, 0, 0);
        acc[3] = __builtin_amdgcn_mfma_f32_16x16x32_bf16(av, bv3, acc[3], 0, 0, 0);
        if (ks < 23) {
            int wb = rb + 1; if (wb == 3) wb = 0;
            sm.st.B[wb][bq0][bco] = c0;
            sm.st.B[wb][bq0 + 1][bco] = c1;
        }
        c0 = n0; c1 = n1;
        rb = rb + 1; if (rb == 3) rb = 0;
        barrier_lgkm();
    }

    // ---- epilogue: relu(acc+bias) into Y (staging dead; full sync below) ----
#pragma unroll
    for (int j = 0; j < 4; ++j) {
        const int co = wc + j * 16 + fr;
        const float bs = bias[co];
#pragma unroll
        for (int q = 0; q < 4; ++q)
            sm.Y[wr + fg * 4 + q][co] = fmaxf(acc[j][q] + bs, 0.f);
    }
    __syncthreads();

    // ---- per-row LayerNorm; wave wv handles rows wv*4..wv*4+3 ----
    const float4 gv = *(const float4*)&g[lane * 4];
    const float4 bvv = *(const float4*)&b[lane * 4];
    float4 lwv = {0.f, 0.f, 0.f, 0.f};
    if (FINAL) lwv = *(const float4*)&lw[lane * 4];
#pragma unroll
    for (int rr = 0; rr < 4; ++rr) {
        const int r = wv * 4 + rr;
        float4 v = *(const float4*)&sm.Y[r][lane * 4];
        float s = v.x + v.y + v.z + v.w;
        float ss = v.x * v.x + v.y * v.y + v.z * v.z + v.w * v.w;
#pragma unroll
        for (int off = 32; off; off >>= 1) {
            s += __shfl_xor(s, off);
            ss += __shfl_xor(ss, off);
        }
        const float mu = s * (1.f / D_);
        const float var = ss * (1.f / D_) - mu * mu;
        const float rs = rsqrtf(var + LN_EPS);
        const float o0 = (v.x - mu) * rs * gv.x + bvv.x;
        const float o1 = (v.y - mu) * rs * gv.y + bvv.y;
        const float o2 = (v.z - mu) * rs * gv.z + bvv.z;
        const float o3 = (v.w - mu) * rs * gv.w + bvv.w;
        if (!FINAL) {
            ushort4 o;
            o.x = (unsigned short)f2bf_raw(o0);
            o.y = (unsigned short)f2bf_raw(o1);
            o.z = (unsigned short)f2bf_raw(o2);
            o.w = (unsigned short)f2bf_raw(o3);
            *(ushort4*)((unsigned short*)out_ + (size_t)(row0 + r) * D_ + lane * 4) = o;
        } else {
            float dot = o0 * lwv.x + o1 * lwv.y + o2 * lwv.z + o3 * lwv.w;
#pragma unroll
            for (int off = 32; off; off >>= 1) dot += __shfl_xor(dot, off);
            if (lane == 0) ((float*)out_)[row0 + r] = dot + lb[0];
        }
    }
}

// ---------------------------------------------------------------- launch ----
extern "C" void kernel_launch(void* const* d_in, const int* in_sizes, int n_in,
                              void* d_out, int out_size, void* d_ws, size_t ws_size,
                              hipStream_t stream) {
    const float* x   = (const float*)d_in[0];
    const float* w1  = (const float*)d_in[1];
    const float* b1  = (const float*)d_in[2];
    const float* g1  = (const float*)d_in[3];
    const float* be1 = (const float*)d_in[4];
    const float* w2  = (const float*)d_in[5];
    const float* b2  = (const float*)d_in[6];
    const float* g2  = (const float*)d_in[7];
    const float* be2 = (const float*)d_in[8];
    const float* lw  = (const float*)d_in[9];
    const float* lb  = (const float*)d_in[10];
    const int* target = (const int*)d_in[11];

    float* out0 = (float*)d_out;                        // [16, 3584, 256]
    float* log_dur = out0 + (size_t)N_ * M_ * D_;       // [16, 512]

    const size_t E = (size_t)N_ * L_ * D_;
    unsigned short* h1b = (unsigned short*)d_ws;        // [E] bf16
    unsigned short* w1t = h1b + E;                      // [24*8192] bf16
    unsigned short* w2t = w1t + 24 * 8192;              // [24*8192] bf16
    int* ends = (int*)(w2t + 24 * 8192);                // [16*512]

    prep_kernel<<<208, 512, 0, stream>>>(w1, w1t, w2, w2t, target, ends);
    conv_gather<false, false><<<512, 512, 0, stream>>>(
        x, w1t, b1, g1, be1, nullptr, nullptr, h1b, x, ends, out0, 0);
    conv_gather<true, true><<<512, 512, 0, stream>>>(
        h1b, w2t, b2, g2, be2, lw, lb, log_dur, x, ends, out0, M_ / 2);
}